// Round 7
// baseline (135.550 us; speedup 1.0000x reference)
//
#include <hip/hip_runtime.h>
#include <stdint.h>

#define H 8
#define DH 96
#define L 2048
#define NB 2
#define D 768

typedef unsigned short u16;
typedef unsigned int u32;
typedef __attribute__((ext_vector_type(8))) __bf16 bf16x8;
typedef __attribute__((ext_vector_type(4))) float f32x4;
typedef __attribute__((ext_vector_type(4))) u32 u32x4;
typedef __attribute__((ext_vector_type(2))) u32 u32x2;
typedef __attribute__((ext_vector_type(4))) u16 u16x4;

// softmax scale folded with log2(e): 96^-0.5 * 1.4426950408889634
#define QSCALE 0.14724444f

static __device__ __forceinline__ u16 f2bf(float f) {
  union { __bf16 h; u16 u; } v;
  v.h = (__bf16)f;
  return v.u;
}

static __device__ __forceinline__ bf16x8 cvt8r(f32x4 a, f32x4 b) {
  bf16x8 r;
  r[0] = (__bf16)a[0]; r[1] = (__bf16)a[1]; r[2] = (__bf16)a[2]; r[3] = (__bf16)a[3];
  r[4] = (__bf16)b[0]; r[5] = (__bf16)b[1]; r[6] = (__bf16)b[2]; r[7] = (__bf16)b[3];
  return r;
}

// ---------------------------------------------------------------------------
// Fused QKV projection + RoPE (z=0: Q, z=1: K, z=2: V->V^T)
// Register-prefetch + double-buffered LDS, ONE barrier per K-step.
// ---------------------------------------------------------------------------
__global__ __launch_bounds__(256, 2)
void proj_qkv(const float* __restrict__ Qin, const float* __restrict__ Kin,
              const float* __restrict__ Vin,
              const float* __restrict__ Wq, const float* __restrict__ Wk,
              const float* __restrict__ Wv,
              const float* __restrict__ cq, const float* __restrict__ ck,
              u16* __restrict__ qo, u16* __restrict__ ko, u16* __restrict__ vo)
{
  __shared__ u16 a_lds[2][128 * 40];
  __shared__ u16 b_lds[2][128 * 40];
  const int tid = threadIdx.x;
  const int lane = tid & 63;
  const int w = tid >> 6;
  const int wr = w >> 1, wc = w & 1;
  const int z = blockIdx.z;
  const int row0 = blockIdx.y * 128;
  const int col0 = blockIdx.x * 128;

  const float* A = (z == 0) ? Qin : ((z == 1) ? Kin : Vin);
  const float* W = (z == 0) ? Wq : ((z == 1) ? Wk : Wv);

  f32x4 acc[4][4] = {};

  const int srow = tid >> 2;         // 0..63
  const int scol = (tid & 3) * 8;    // 0,8,16,24
  const float* pA  = A + (size_t)(row0 + srow) * D + scol;
  const float* pA2 = A + (size_t)(row0 + srow + 64) * D + scol;
  const float* pW  = W + (size_t)(col0 + srow) * D + scol;
  const float* pW2 = W + (size_t)(col0 + srow + 64) * D + scol;
  const int fr = lane & 15;
  const int fk = (lane >> 4) * 8;

  f32x4 fa[4], fb[4];
  // prologue: tile k0=0 -> regs -> buf 0
  fa[0] = *(const f32x4*)(pA);      fa[1] = *(const f32x4*)(pA + 4);
  fa[2] = *(const f32x4*)(pA2);     fa[3] = *(const f32x4*)(pA2 + 4);
  fb[0] = *(const f32x4*)(pW);      fb[1] = *(const f32x4*)(pW + 4);
  fb[2] = *(const f32x4*)(pW2);     fb[3] = *(const f32x4*)(pW2 + 4);
  *(bf16x8*)(&a_lds[0][srow * 40 + scol]) = cvt8r(fa[0], fa[1]);
  *(bf16x8*)(&a_lds[0][(srow + 64) * 40 + scol]) = cvt8r(fa[2], fa[3]);
  *(bf16x8*)(&b_lds[0][srow * 40 + scol]) = cvt8r(fb[0], fb[1]);
  *(bf16x8*)(&b_lds[0][(srow + 64) * 40 + scol]) = cvt8r(fb[2], fb[3]);
  __syncthreads();

  int cur = 0;
  for (int k0 = 0; k0 < D; k0 += 32) {
    const int nk = k0 + 32;
    if (nk < D) {  // issue next tile's loads; latency hides under compute
      fa[0] = *(const f32x4*)(pA + nk);      fa[1] = *(const f32x4*)(pA + nk + 4);
      fa[2] = *(const f32x4*)(pA2 + nk);     fa[3] = *(const f32x4*)(pA2 + nk + 4);
      fb[0] = *(const f32x4*)(pW + nk);      fb[1] = *(const f32x4*)(pW + nk + 4);
      fb[2] = *(const f32x4*)(pW2 + nk);     fb[3] = *(const f32x4*)(pW2 + nk + 4);
    }
    bf16x8 af[4], bfr[4];
#pragma unroll
    for (int m = 0; m < 4; m++)
      af[m] = *(const bf16x8*)(&a_lds[cur][(wr * 64 + m * 16 + fr) * 40 + fk]);
#pragma unroll
    for (int n = 0; n < 4; n++)
      bfr[n] = *(const bf16x8*)(&b_lds[cur][(wc * 64 + n * 16 + fr) * 40 + fk]);
#pragma unroll
    for (int m = 0; m < 4; m++)
#pragma unroll
      for (int n = 0; n < 4; n++)
        acc[m][n] = __builtin_amdgcn_mfma_f32_16x16x32_bf16(af[m], bfr[n], acc[m][n], 0, 0, 0);
    if (nk < D) {  // write into the buffer last read at k0-32 (safe: prev barrier)
      *(bf16x8*)(&a_lds[cur ^ 1][srow * 40 + scol]) = cvt8r(fa[0], fa[1]);
      *(bf16x8*)(&a_lds[cur ^ 1][(srow + 64) * 40 + scol]) = cvt8r(fa[2], fa[3]);
      *(bf16x8*)(&b_lds[cur ^ 1][srow * 40 + scol]) = cvt8r(fb[0], fb[1]);
      *(bf16x8*)(&b_lds[cur ^ 1][(srow + 64) * 40 + scol]) = cvt8r(fb[2], fb[3]);
    }
    __syncthreads();
    cur ^= 1;
  }

  if (z == 2) {
#pragma unroll
    for (int m = 0; m < 4; m++) {
      int rbase = row0 + wr * 64 + m * 16 + (lane >> 4) * 4;
#pragma unroll
      for (int n = 0; n < 4; n++) {
        int c = col0 + wc * 64 + n * 16 + fr;
        int hh = c / DH, dd = c % DH;
#pragma unroll
        for (int r = 0; r < 4; r++) {
          int row = rbase + r;
          int b = row >> 11, l = row & (L - 1);
          vo[((size_t)((b * H + hh) * DH + dd)) * L + l] = f2bf(acc[m][n][r]);
        }
      }
    }
  } else {
    const float* coords = (z == 0) ? cq : ck;
    u16* outp = (z == 0) ? qo : ko;
    const float postscale = (z == 0) ? QSCALE : 1.0f;
#pragma unroll
    for (int m = 0; m < 4; m++) {
      int rbase = row0 + wr * 64 + m * 16 + (lane >> 4) * 4;
#pragma unroll
      for (int np = 0; np < 2; np++) {
        int n1 = np * 2;
        int c1 = col0 + wc * 64 + n1 * 16 + fr;
        int hh = c1 / DH;
        int dd1 = c1 % DH;
        int axis = dd1 / 32;
        int j = dd1 & 15;
        float invf = exp2f(-(float)j * 0.83048202372184058f);
#pragma unroll
        for (int r = 0; r < 4; r++) {
          int row = rbase + r;
          int b = row >> 11, l = row & (L - 1);
          float coord = coords[((size_t)(b * L + l)) * 3 + axis];
          float ang = coord * invf;
          float sn = __sinf(ang), cs = __cosf(ang);
          float x1 = acc[m][n1][r], x2 = acc[m][n1 + 1][r];
          size_t base = ((size_t)((b * H + hh) * L + l)) * DH;
          outp[base + dd1] = f2bf((x1 * cs - x2 * sn) * postscale);
          outp[base + dd1 + 16] = f2bf((x1 * sn + x2 * cs) * postscale);
        }
      }
    }
  }
}

// ---------------------------------------------------------------------------
// Flash attention, swapped-operand QK^T, 32 q-rows/wave (2 q-subtiles share
// every K/V fragment read -> LDS reads per MFMA halved). One barrier/tile.
// ---------------------------------------------------------------------------
#define KSTR 104
#define VSTR 72
#define NT   (L / 64)
__global__ __launch_bounds__(256, 2)
void attn_fwd(const u16* __restrict__ q_ws, const u16* __restrict__ k_ws,
              const u16* __restrict__ vt_ws, u16* __restrict__ ao)
{
  __shared__ u16 k_lds[2][64 * KSTR];
  __shared__ u16 vt_lds[2][96 * VSTR];
  const int tid = threadIdx.x;
  const int lane = tid & 63;
  const int w = tid >> 6;
  const int bh = blockIdx.y;
  const int q0 = blockIdx.x * 128;

  const int fr = lane & 15;
  const int hi = lane >> 4;
  const int fko = hi * 8;

  // staging offsets (K natural; V^T columns sigma-permuted in 4-chunks)
  int kg_off[3], kl_off[3], vg_off[3], vl0_off[3], vl1_off[3];
#pragma unroll
  for (int it = 0; it < 3; it++) {
    int ch = tid + it * 256;
    int krow = ch / 12, koff = (ch % 12) * 8;
    kg_off[it] = krow * DH + koff;
    kl_off[it] = krow * KSTR + koff;
    int vrow = ch >> 3, vq = (ch & 7) * 2;
    vg_off[it] = vrow * L + vq * 4;
    int s0 = ((vq >> 3) << 5) | ((vq & 3) << 3) | (((vq >> 2) & 1) << 2);
    int vq1 = vq + 1;
    int s1 = ((vq1 >> 3) << 5) | ((vq1 & 3) << 3) | (((vq1 >> 2) & 1) << 2);
    vl0_off[it] = vrow * VSTR + s0;
    vl1_off[it] = vrow * VSTR + s1;
  }

  // Q fragments for the two 16-row subtiles
  bf16x8 qf0[3], qf1[3];
  const u16* qb0 = q_ws + ((size_t)bh * L + q0 + w * 32 + fr) * DH;
  const u16* qb1 = qb0 + 16 * DH;
#pragma unroll
  for (int ks = 0; ks < 3; ks++) {
    qf0[ks] = *(const bf16x8*)(qb0 + ks * 32 + fko);
    qf1[ks] = *(const bf16x8*)(qb1 + ks * 32 + fko);
  }

  f32x4 o0[6] = {}, o1[6] = {};
  float m0 = -1e30f, l0 = 0.f, m1 = -1e30f, l1 = 0.f;

  const u16* kbase = k_ws + (size_t)bh * L * DH;
  const u16* vtbase = vt_ws + (size_t)bh * DH * L;

  u32x4 kreg[3], vreg[3];
#pragma unroll
  for (int it = 0; it < 3; it++) {
    kreg[it] = *(const u32x4*)(kbase + kg_off[it]);
    vreg[it] = *(const u32x4*)(vtbase + vg_off[it]);
  }
#pragma unroll
  for (int it = 0; it < 3; it++) {
    *(u32x4*)(&k_lds[0][kl_off[it]]) = kreg[it];
    u32x2 lo = { vreg[it][0], vreg[it][1] };
    u32x2 hi2 = { vreg[it][2], vreg[it][3] };
    *(u32x2*)(&vt_lds[0][vl0_off[it]]) = lo;
    *(u32x2*)(&vt_lds[0][vl1_off[it]]) = hi2;
  }
  __syncthreads();

  int cur = 0;
  for (int t = 0; t < NT; t++) {
    if (t + 1 < NT) {
      const u16* kb = kbase + (size_t)(t + 1) * 64 * DH;
      const u16* vb = vtbase + (t + 1) * 64;
#pragma unroll
      for (int it = 0; it < 3; it++) {
        kreg[it] = *(const u32x4*)(kb + kg_off[it]);
        vreg[it] = *(const u32x4*)(vb + vg_off[it]);
      }
    }

    // S^T = K Q^T for both q-subtiles; each kfrag feeds 2 MFMAs
    f32x4 s0[4] = {}, s1[4] = {};
#pragma unroll
    for (int ks = 0; ks < 3; ks++)
#pragma unroll
      for (int kf = 0; kf < 4; kf++) {
        bf16x8 kfrag = *(const bf16x8*)(&k_lds[cur][(kf * 16 + fr) * KSTR + ks * 32 + fko]);
        s0[kf] = __builtin_amdgcn_mfma_f32_16x16x32_bf16(kfrag, qf0[ks], s0[kf], 0, 0, 0);
        s1[kf] = __builtin_amdgcn_mfma_f32_16x16x32_bf16(kfrag, qf1[ks], s1[kf], 0, 0, 0);
      }

    // lane-local online softmax, subtile 0
    bf16x8 pt0[2], pt1[2];
    {
      float mx = fmaxf(fmaxf(s0[0][0], s0[0][1]), fmaxf(s0[0][2], s0[0][3]));
#pragma unroll
      for (int kf = 1; kf < 4; kf++)
        mx = fmaxf(mx, fmaxf(fmaxf(s0[kf][0], s0[kf][1]), fmaxf(s0[kf][2], s0[kf][3])));
      mx = fmaxf(mx, __shfl_xor(mx, 16));
      mx = fmaxf(mx, __shfl_xor(mx, 32));
      float mn = fmaxf(m0, mx);
      float alpha = exp2f(m0 - mn);
      m0 = mn;
      float p[4][4];
      float rs = 0.f;
#pragma unroll
      for (int kf = 0; kf < 4; kf++)
#pragma unroll
        for (int r = 0; r < 4; r++) {
          float pv = exp2f(s0[kf][r] - mn);
          p[kf][r] = pv;
          rs += pv;
        }
      rs += __shfl_xor(rs, 16);
      rs += __shfl_xor(rs, 32);
      l0 = l0 * alpha + rs;
#pragma unroll
      for (int df = 0; df < 6; df++)
#pragma unroll
        for (int r = 0; r < 4; r++)
          o0[df][r] *= alpha;
#pragma unroll
      for (int ks = 0; ks < 2; ks++)
#pragma unroll
        for (int j = 0; j < 8; j++)
          pt0[ks][j] = (__bf16)p[2 * ks + (j >> 2)][j & 3];
    }
    // subtile 1
    {
      float mx = fmaxf(fmaxf(s1[0][0], s1[0][1]), fmaxf(s1[0][2], s1[0][3]));
#pragma unroll
      for (int kf = 1; kf < 4; kf++)
        mx = fmaxf(mx, fmaxf(fmaxf(s1[kf][0], s1[kf][1]), fmaxf(s1[kf][2], s1[kf][3])));
      mx = fmaxf(mx, __shfl_xor(mx, 16));
      mx = fmaxf(mx, __shfl_xor(mx, 32));
      float mn = fmaxf(m1, mx);
      float alpha = exp2f(m1 - mn);
      m1 = mn;
      float p[4][4];
      float rs = 0.f;
#pragma unroll
      for (int kf = 0; kf < 4; kf++)
#pragma unroll
        for (int r = 0; r < 4; r++) {
          float pv = exp2f(s1[kf][r] - mn);
          p[kf][r] = pv;
          rs += pv;
        }
      rs += __shfl_xor(rs, 16);
      rs += __shfl_xor(rs, 32);
      l1 = l1 * alpha + rs;
#pragma unroll
      for (int df = 0; df < 6; df++)
#pragma unroll
        for (int r = 0; r < 4; r++)
          o1[df][r] *= alpha;
#pragma unroll
      for (int ks = 0; ks < 2; ks++)
#pragma unroll
        for (int j = 0; j < 8; j++)
          pt1[ks][j] = (__bf16)p[2 * ks + (j >> 2)][j & 3];
    }

    // O^T += V P^T; each vfrag feeds 2 MFMAs
#pragma unroll
    for (int ks = 0; ks < 2; ks++)
#pragma unroll
      for (int df = 0; df < 6; df++) {
        bf16x8 vfrag = *(const bf16x8*)(&vt_lds[cur][(df * 16 + fr) * VSTR + ks * 32 + fko]);
        o0[df] = __builtin_amdgcn_mfma_f32_16x16x32_bf16(vfrag, pt0[ks], o0[df], 0, 0, 0);
        o1[df] = __builtin_amdgcn_mfma_f32_16x16x32_bf16(vfrag, pt1[ks], o1[df], 0, 0, 0);
      }

    if (t + 1 < NT) {  // write buf last read at t-1 (ordered by prev barrier)
#pragma unroll
      for (int it = 0; it < 3; it++) {
        *(u32x4*)(&k_lds[cur ^ 1][kl_off[it]]) = kreg[it];
        u32x2 lo = { vreg[it][0], vreg[it][1] };
        u32x2 hi2 = { vreg[it][2], vreg[it][3] };
        *(u32x2*)(&vt_lds[cur ^ 1][vl0_off[it]]) = lo;
        *(u32x2*)(&vt_lds[cur ^ 1][vl1_off[it]]) = hi2;
      }
    }
    __syncthreads();
    cur ^= 1;
  }

  // epilogue
  const int b = bh >> 3, hh = bh & 7;
  {
    const int l = q0 + w * 32 + fr;
    const float inv = 1.f / l0;
    u16* aop = ao + ((size_t)(b * L + l)) * D + hh * DH + hi * 4;
#pragma unroll
    for (int df = 0; df < 6; df++) {
      u16x4 pk;
#pragma unroll
      for (int r = 0; r < 4; r++)
        pk[r] = f2bf(o0[df][r] * inv);
      *(u16x4*)(aop + df * 16) = pk;
    }
  }
  {
    const int l = q0 + w * 32 + 16 + fr;
    const float inv = 1.f / l1;
    u16* aop = ao + ((size_t)(b * L + l)) * D + hh * DH + hi * 4;
#pragma unroll
    for (int df = 0; df < 6; df++) {
      u16x4 pk;
#pragma unroll
      for (int r = 0; r < 4; r++)
        pk[r] = f2bf(o1[df][r] * inv);
      *(u16x4*)(aop + df * 16) = pk;
    }
  }
}

// ---------------------------------------------------------------------------
// Output projection: out = AO @ Wo^T; 64x64 tiles, prefetch + dbuf LDS,
// one barrier per K-step.
// ---------------------------------------------------------------------------
__global__ __launch_bounds__(256, 2)
void gemm_out(const u16* __restrict__ A, const float* __restrict__ W,
              float* __restrict__ out)
{
  __shared__ u16 a_lds[2][64 * 40];
  __shared__ u16 b_lds[2][64 * 40];
  const int tid = threadIdx.x;
  const int lane = tid & 63;
  const int w = tid >> 6;
  const int wr = w >> 1, wc = w & 1;
  const int row0 = blockIdx.y * 64;
  const int col0 = blockIdx.x * 64;

  f32x4 acc[2][2] = {};
  const int srow = tid >> 2;
  const int scol = (tid & 3) * 8;
  const u16* pA = A + (size_t)(row0 + srow) * D + scol;
  const float* pW = W + (size_t)(col0 + srow) * D + scol;
  const int fr = lane & 15;
  const int fk = (lane >> 4) * 8;

  u32x4 ra;
  f32x4 rb0, rb1;
  ra  = *(const u32x4*)(pA);
  rb0 = *(const f32x4*)(pW);
  rb1 = *(const f32x4*)(pW + 4);
  *(u32x4*)(&a_lds[0][srow * 40 + scol]) = ra;
  *(bf16x8*)(&b_lds[0][srow * 40 + scol]) = cvt8r(rb0, rb1);
  __syncthreads();

  int cur = 0;
  for (int k0 = 0; k0 < D; k0 += 32) {
    const int nk = k0 + 32;
    if (nk < D) {
      ra  = *(const u32x4*)(pA + nk);
      rb0 = *(const f32x4*)(pW + nk);
      rb1 = *(const f32x4*)(pW + nk + 4);
    }
    bf16x8 af[2], bfr[2];
#pragma unroll
    for (int m = 0; m < 2; m++)
      af[m] = *(const bf16x8*)(&a_lds[cur][(wr * 32 + m * 16 + fr) * 40 + fk]);
#pragma unroll
    for (int n = 0; n < 2; n++)
      bfr[n] = *(const bf16x8*)(&b_lds[cur][(wc * 32 + n * 16 + fr) * 40 + fk]);
#pragma unroll
    for (int m = 0; m < 2; m++)
#pragma unroll
      for (int n = 0; n < 2; n++)
        acc[m][n] = __builtin_amdgcn_mfma_f32_16x16x32_bf16(af[m], bfr[n], acc[m][n], 0, 0, 0);
    if (nk < D) {
      *(u32x4*)(&a_lds[cur ^ 1][srow * 40 + scol]) = ra;
      *(bf16x8*)(&b_lds[cur ^ 1][srow * 40 + scol]) = cvt8r(rb0, rb1);
    }
    __syncthreads();
    cur ^= 1;
  }

#pragma unroll
  for (int m = 0; m < 2; m++) {
    int rbase = row0 + wr * 32 + m * 16 + (lane >> 4) * 4;
#pragma unroll
    for (int n = 0; n < 2; n++) {
      int c = col0 + wc * 32 + n * 16 + fr;
#pragma unroll
      for (int r = 0; r < 4; r++)
        out[(size_t)(rbase + r) * D + c] = acc[m][n][r];
    }
  }
}

extern "C" void kernel_launch(void* const* d_in, const int* in_sizes, int n_in,
                              void* d_out, int out_size, void* d_ws, size_t ws_size,
                              hipStream_t stream) {
  (void)in_sizes; (void)n_in; (void)out_size;
  const float* Qin = (const float*)d_in[0];
  const float* Kin = (const float*)d_in[1];
  const float* Vin = (const float*)d_in[2];
  const float* cq  = (const float*)d_in[3];
  const float* ck  = (const float*)d_in[4];
  const float* Wq  = (const float*)d_in[5];
  const float* Wk  = (const float*)d_in[6];
  const float* Wv  = (const float*)d_in[7];
  const float* Wo  = (const float*)d_in[8];
  float* out = (float*)d_out;

  const size_t per = (size_t)NB * H * L * DH;  // 3,145,728 elems
  if (ws_size < 4 * per * sizeof(u16)) return;

  u16* q_ws  = (u16*)d_ws;
  u16* k_ws  = q_ws + per;
  u16* vt_ws = k_ws + per;
  u16* ao_ws = vt_ws + per;

  dim3 blk(256);
  proj_qkv<<<dim3(D / 128, (NB * L) / 128, 3), blk, 0, stream>>>(
      Qin, Kin, Vin, Wq, Wk, Wv, cq, ck, q_ws, k_ws, vt_ws);
  attn_fwd<<<dim3(L / 128, NB * H), blk, 0, stream>>>(q_ws, k_ws, vt_ws, ao_ws);
  gemm_out<<<dim3(D / 64, (NB * L) / 64), blk, 0, stream>>>(ao_ws, Wo, out);
}